// Round 3
// baseline (459.034 us; speedup 1.0000x reference)
//
#include <hip/hip_runtime.h>
#include <math.h>

// ---------------------------------------------------------------------------
// GCN: 4x (bf16-MFMA GEMM -> symmetric-normalized aggregation (+bias, lrelu))
//      -> softmax.  Graph prep per call: degree -> rsqrt -> scan -> CSR(src only).
// norm is never materialized: out[n] = dis[n]*(sum_e dis[s]*h[s] + dis[n]*h[n]).
// ---------------------------------------------------------------------------

typedef unsigned short ushort_t;
typedef unsigned int   uint_t;
typedef short  bf16x8 __attribute__((ext_vector_type(8)));
typedef float  f32x4  __attribute__((ext_vector_type(4)));

__device__ __forceinline__ ushort_t f2bf(float f) {
    union { float f; uint_t u; } v; v.f = f;
    uint_t u = v.u;
    u += 0x7fffu + ((u >> 16) & 1u);      // round-to-nearest-even
    return (ushort_t)(u >> 16);
}
__device__ __forceinline__ float bflo(uint_t u) {
    union { uint_t q; float f; } v; v.q = u << 16; return v.f;
}
__device__ __forceinline__ float bfhi(uint_t u) {
    union { uint_t q; float f; } v; v.q = u & 0xffff0000u; return v.f;
}

// ------------------------------- graph prep -------------------------------

__global__ void deg_count_kernel(const int* __restrict__ dst, int* __restrict__ degi, int E) {
    int e = blockIdx.x * blockDim.x + threadIdx.x;
    if (e < E) atomicAdd(&degi[dst[e]], 1);
}

__global__ void dis_kernel(const int* __restrict__ degi, float* __restrict__ dis, int n) {
    int i = blockIdx.x * blockDim.x + threadIdx.x;
    if (i < n) dis[i] = rsqrtf((float)(degi[i] + 1));  // +1 self-loop
}

// hierarchical exclusive scan: per-1024-block scan + block sums
__global__ void scan_block_kernel(const int* __restrict__ degi, int* __restrict__ row_excl,
                                  int* __restrict__ bsums, int n) {
    __shared__ int buf[1024];
    int i = blockIdx.x * 1024 + threadIdx.x;
    int v = (i < n) ? degi[i] : 0;
    buf[threadIdx.x] = v;
    __syncthreads();
    for (int off = 1; off < 1024; off <<= 1) {
        int t = (threadIdx.x >= (unsigned)off) ? buf[threadIdx.x - off] : 0;
        __syncthreads();
        buf[threadIdx.x] += t;
        __syncthreads();
    }
    if (i < n) row_excl[i] = buf[threadIdx.x] - v;
    if (threadIdx.x == 1023) bsums[blockIdx.x] = buf[1023];
}

// single block, nb <= 128: exclusive scan of bsums in place, total at bsums[nb]
__global__ void scan_sums_kernel(int* __restrict__ bsums, int nb) {
    __shared__ int buf[128];
    int v = ((int)threadIdx.x < nb) ? bsums[threadIdx.x] : 0;
    buf[threadIdx.x] = v;
    __syncthreads();
    for (int off = 1; off < 128; off <<= 1) {
        int t = (threadIdx.x >= (unsigned)off) ? buf[threadIdx.x - off] : 0;
        __syncthreads();
        buf[threadIdx.x] += t;
        __syncthreads();
    }
    if ((int)threadIdx.x < nb) bsums[threadIdx.x] = buf[threadIdx.x] - v;
    if (threadIdx.x == 0) bsums[nb] = buf[127];
}

__global__ void scan_add_kernel(int* __restrict__ row_start, const int* __restrict__ bsums,
                                int n, int nb) {
    int i = blockIdx.x * blockDim.x + threadIdx.x;
    if (i < n) row_start[i] += bsums[i >> 10];
    else if (i == n) row_start[n] = bsums[nb];
}

// scatter src ids into CSR; reuses degi as the cursor (atomicSub -> old in [1,deg])
__global__ void scatter_kernel(const int* __restrict__ srcArr, const int* __restrict__ dstArr,
                               const int* __restrict__ row_start, int* __restrict__ degi,
                               int* __restrict__ csr_src, int E) {
    int e = blockIdx.x * blockDim.x + threadIdx.x;
    if (e >= E) return;
    int s = srcArr[e], d = dstArr[e];
    int p = atomicSub(&degi[d], 1) - 1;           // in [0, deg)
    csr_src[row_start[d] + p] = s;
}

// ------------------------------ dtype converts ----------------------------

// W [K x N] fp32 -> Wt [NP x KP] bf16 (transposed + zero-padded)
__global__ void wt_kernel(const float* __restrict__ W, ushort_t* __restrict__ Wt,
                          int K, int N, int KP, int NP) {
    int idx = blockIdx.x * blockDim.x + threadIdx.x;
    if (idx >= KP * NP) return;
    int n = idx / KP, k = idx % KP;
    float v = (k < K && n < N) ? W[(size_t)k * N + n] : 0.f;
    Wt[(size_t)n * KP + k] = f2bf(v);
}

// ------------------------------ MFMA GEMM ---------------------------------
// C[M x nstore] (bf16, stride ldc) = A[M x K] @ Bt[NP x K]^T (bf16, N-major)
// A is bf16 (lda stride) or fp32 (A_FP32: converted while staging to LDS).
// BM=128 BN=64 BK=64, 4 waves (2Mx2N), per-wave 64x32 out (4x2 frags).
template <bool A_FP32>
__global__ __launch_bounds__(256) void mfma_gemm(const void* __restrict__ Av,
                                                 const ushort_t* __restrict__ Bt,
                                                 ushort_t* __restrict__ C,
                                                 int M, int K, int lda, int ldb,
                                                 int ldc, int nstore) {
    __shared__ __attribute__((aligned(16))) ushort_t As[128][72];  // +8 pad
    __shared__ __attribute__((aligned(16))) ushort_t Bs[64][72];

    const int t    = threadIdx.x;
    const int lane = t & 63;
    const int w    = t >> 6;
    const int wm   = w >> 1, wn = w & 1;
    const int m0   = blockIdx.x * 128;
    const int n0   = blockIdx.y * 64;

    f32x4 acc[4][2];
    #pragma unroll
    for (int mi = 0; mi < 4; ++mi)
        #pragma unroll
        for (int ni = 0; ni < 2; ++ni) acc[mi][ni] = (f32x4){0.f, 0.f, 0.f, 0.f};

    const int srow = t >> 3;          // 0..31
    const int scol = (t & 7) * 8;     // 0..56

    for (int k0 = 0; k0 < K; k0 += 64) {
        #pragma unroll
        for (int it = 0; it < 4; ++it) {            // A tile 128x64
            int r = srow + it * 32;
            int gm = m0 + r;
            bf16x8 v = {0, 0, 0, 0, 0, 0, 0, 0};
            if (gm < M) {
                if (A_FP32) {
                    const float* A = (const float*)Av;
                    const float4 f0 = *(const float4*)(A + (size_t)gm * lda + k0 + scol);
                    const float4 f1 = *(const float4*)(A + (size_t)gm * lda + k0 + scol + 4);
                    ushort_t o[8] = { f2bf(f0.x), f2bf(f0.y), f2bf(f0.z), f2bf(f0.w),
                                      f2bf(f1.x), f2bf(f1.y), f2bf(f1.z), f2bf(f1.w) };
                    v = *(const bf16x8*)o;
                } else {
                    const ushort_t* A = (const ushort_t*)Av;
                    v = *(const bf16x8*)(A + (size_t)gm * lda + k0 + scol);
                }
            }
            *(bf16x8*)&As[r][scol] = v;
        }
        #pragma unroll
        for (int it = 0; it < 2; ++it) {            // B tile 64x64 (rows padded)
            int r = srow + it * 32;
            bf16x8 v = *(const bf16x8*)(Bt + (size_t)(n0 + r) * ldb + k0 + scol);
            *(bf16x8*)&Bs[r][scol] = v;
        }
        __syncthreads();
        #pragma unroll
        for (int kk = 0; kk < 2; ++kk) {
            bf16x8 af[4], bfr[2];
            const int kc = kk * 32 + (lane >> 4) * 8;
            #pragma unroll
            for (int mi = 0; mi < 4; ++mi)
                af[mi] = *(const bf16x8*)&As[wm * 64 + mi * 16 + (lane & 15)][kc];
            #pragma unroll
            for (int ni = 0; ni < 2; ++ni)
                bfr[ni] = *(const bf16x8*)&Bs[wn * 32 + ni * 16 + (lane & 15)][kc];
            #pragma unroll
            for (int mi = 0; mi < 4; ++mi)
                #pragma unroll
                for (int ni = 0; ni < 2; ++ni)
                    acc[mi][ni] = __builtin_amdgcn_mfma_f32_16x16x32_bf16(
                        af[mi], bfr[ni], acc[mi][ni], 0, 0, 0);
        }
        __syncthreads();
    }

    // C/D layout: col = lane&15, row = (lane>>4)*4 + r
    #pragma unroll
    for (int mi = 0; mi < 4; ++mi)
        #pragma unroll
        for (int ni = 0; ni < 2; ++ni)
            #pragma unroll
            for (int r = 0; r < 4; ++r) {
                int gm = m0 + wm * 64 + mi * 16 + (lane >> 4) * 4 + r;
                int gn = n0 + wn * 32 + ni * 16 + (lane & 15);
                if (gm < M && gn < nstore)
                    C[(size_t)gm * ldc + gn] = f2bf(acc[mi][ni][r]);
            }
}

// ---------------------------- aggregation ---------------------------------
// out[n] = lrelu( dn*( sum_e dis[s]*h[s] + dn*h[n] ) + bias )
// FPAD=128: one wave per node, lane holds features {2l, 2l+1}.
template <int F>
__global__ void aggregate128_kernel(const ushort_t* __restrict__ h, const int* __restrict__ row_start,
                                    const int* __restrict__ csr_src,
                                    const float* __restrict__ dis, const float* __restrict__ bias,
                                    ushort_t* __restrict__ out, int n) {
    int wid  = threadIdx.x >> 6;
    int lane = threadIdx.x & 63;
    int node = blockIdx.x * (blockDim.x >> 6) + wid;
    if (node >= n) return;
    const int f0 = 2 * lane, f1 = f0 + 1;
    float dn = dis[node];
    uint_t v = *(const uint_t*)(h + (size_t)node * 128 + f0);
    float acc0 = bflo(v) * dn;          // self-loop: dn*h[n]; total gets *dn below
    float acc1 = bfhi(v) * dn;
    int i = row_start[node], end = row_start[node + 1];
    for (; i + 4 <= end; i += 4) {
        int s0 = csr_src[i], s1 = csr_src[i + 1], s2 = csr_src[i + 2], s3 = csr_src[i + 3];
        float m0 = dis[s0], m1 = dis[s1], m2 = dis[s2], m3 = dis[s3];
        uint_t u0 = *(const uint_t*)(h + (size_t)s0 * 128 + f0);
        uint_t u1 = *(const uint_t*)(h + (size_t)s1 * 128 + f0);
        uint_t u2 = *(const uint_t*)(h + (size_t)s2 * 128 + f0);
        uint_t u3 = *(const uint_t*)(h + (size_t)s3 * 128 + f0);
        acc0 += bflo(u0) * m0; acc1 += bfhi(u0) * m0;
        acc0 += bflo(u1) * m1; acc1 += bfhi(u1) * m1;
        acc0 += bflo(u2) * m2; acc1 += bfhi(u2) * m2;
        acc0 += bflo(u3) * m3; acc1 += bfhi(u3) * m3;
    }
    for (; i < end; ++i) {
        int s = csr_src[i];
        float nrm = dis[s];
        uint_t u = *(const uint_t*)(h + (size_t)s * 128 + f0);
        acc0 += bflo(u) * nrm; acc1 += bfhi(u) * nrm;
    }
    acc0 = acc0 * dn + ((f0 < F) ? bias[f0] : 0.f);
    acc1 = acc1 * dn + ((f1 < F) ? bias[f1] : 0.f);
    acc0 = (acc0 > 0.f) ? acc0 : 0.1f * acc0;
    acc1 = (acc1 > 0.f) ? acc1 : 0.1f * acc1;
    if (f0 >= F) acc0 = 0.f;   // keep K-padding exactly zero
    if (f1 >= F) acc1 = 0.f;
    uint_t o = (uint_t)f2bf(acc0) | ((uint_t)f2bf(acc1) << 16);
    *(uint_t*)(out + (size_t)node * 128 + f0) = o;
}

// F=32: 16-lane group per node (2 features per lane), 4 nodes per wave.
__global__ void aggregate32_kernel(const ushort_t* __restrict__ h, const int* __restrict__ row_start,
                                   const int* __restrict__ csr_src,
                                   const float* __restrict__ dis, const float* __restrict__ bias,
                                   ushort_t* __restrict__ out, int n) {
    int lane16 = threadIdx.x & 15;
    int node = blockIdx.x * (blockDim.x >> 4) + (threadIdx.x >> 4);
    if (node >= n) return;
    const int f0 = 2 * lane16;
    float dn = dis[node];
    uint_t v = *(const uint_t*)(h + (size_t)node * 32 + f0);
    float acc0 = bflo(v) * dn;
    float acc1 = bfhi(v) * dn;
    int i = row_start[node], end = row_start[node + 1];
    for (; i + 4 <= end; i += 4) {
        int s0 = csr_src[i], s1 = csr_src[i + 1], s2 = csr_src[i + 2], s3 = csr_src[i + 3];
        float m0 = dis[s0], m1 = dis[s1], m2 = dis[s2], m3 = dis[s3];
        uint_t u0 = *(const uint_t*)(h + (size_t)s0 * 32 + f0);
        uint_t u1 = *(const uint_t*)(h + (size_t)s1 * 32 + f0);
        uint_t u2 = *(const uint_t*)(h + (size_t)s2 * 32 + f0);
        uint_t u3 = *(const uint_t*)(h + (size_t)s3 * 32 + f0);
        acc0 += bflo(u0) * m0; acc1 += bfhi(u0) * m0;
        acc0 += bflo(u1) * m1; acc1 += bfhi(u1) * m1;
        acc0 += bflo(u2) * m2; acc1 += bfhi(u2) * m2;
        acc0 += bflo(u3) * m3; acc1 += bfhi(u3) * m3;
    }
    for (; i < end; ++i) {
        int s = csr_src[i];
        float nrm = dis[s];
        uint_t u = *(const uint_t*)(h + (size_t)s * 32 + f0);
        acc0 += bflo(u) * nrm; acc1 += bfhi(u) * nrm;
    }
    acc0 = acc0 * dn + bias[f0];
    acc1 = acc1 * dn + bias[f0 + 1];
    acc0 = (acc0 > 0.f) ? acc0 : 0.1f * acc0;
    acc1 = (acc1 > 0.f) ? acc1 : 0.1f * acc1;
    uint_t o = (uint_t)f2bf(acc0) | ((uint_t)f2bf(acc1) << 16);
    *(uint_t*)(out + (size_t)node * 32 + f0) = o;
}

// layer 4 GEMM: [N x 32] bf16 @ [32 x 2] fp32 -> fp32, one thread per node
__global__ void gemm32x2_kernel(const ushort_t* __restrict__ H, const float* __restrict__ W4,
                                float* __restrict__ C, int n) {
    int node = blockIdx.x * blockDim.x + threadIdx.x;
    if (node >= n) return;
    const uint_t* row = (const uint_t*)(H + (size_t)node * 32);
    float a0 = 0.f, a1 = 0.f;
    #pragma unroll
    for (int k2 = 0; k2 < 16; ++k2) {
        uint_t u = row[k2];
        float x0 = bflo(u), x1 = bfhi(u);
        int k = 2 * k2;
        a0 += x0 * W4[k * 2]     + x1 * W4[(k + 1) * 2];
        a1 += x0 * W4[k * 2 + 1] + x1 * W4[(k + 1) * 2 + 1];
    }
    C[2 * (size_t)node] = a0;
    C[2 * (size_t)node + 1] = a1;
}

// final aggregation (F=2) + bias + softmax, one thread per node
__global__ void aggregate2_softmax_kernel(const float* __restrict__ h, const int* __restrict__ row_start,
                                          const int* __restrict__ csr_src,
                                          const float* __restrict__ dis, const float* __restrict__ bias,
                                          float* __restrict__ out, int n) {
    int node = blockIdx.x * blockDim.x + threadIdx.x;
    if (node >= n) return;
    float dn = dis[node];
    float a0 = h[2 * (size_t)node]     * dn;
    float a1 = h[2 * (size_t)node + 1] * dn;
    int beg = row_start[node], end = row_start[node + 1];
    for (int i = beg; i < end; ++i) {
        int s = csr_src[i];
        float nrm = dis[s];
        a0 += h[2 * (size_t)s]     * nrm;
        a1 += h[2 * (size_t)s + 1] * nrm;
    }
    a0 = a0 * dn + bias[0];
    a1 = a1 * dn + bias[1];
    float m  = fmaxf(a0, a1);
    float e0 = expf(a0 - m), e1 = expf(a1 - m);
    float inv = 1.f / (e0 + e1);
    out[2 * (size_t)node]     = e0 * inv;
    out[2 * (size_t)node + 1] = e1 * inv;
}

// ---------------------------------------------------------------------------

extern "C" void kernel_launch(void* const* d_in, const int* in_sizes, int n_in,
                              void* d_out, int out_size, void* d_ws, size_t ws_size,
                              hipStream_t stream) {
    const float* x  = (const float*)d_in[0];
    const int*   ei = (const int*)d_in[1];
    const float* W1 = (const float*)d_in[2];
    const float* b1 = (const float*)d_in[3];
    const float* W2 = (const float*)d_in[4];
    const float* b2 = (const float*)d_in[5];
    const float* W3 = (const float*)d_in[6];
    const float* b3 = (const float*)d_in[7];
    const float* W4 = (const float*)d_in[8];
    const float* b4 = (const float*)d_in[9];

    const int N = in_sizes[0] / 256;
    const int E = in_sizes[1] / 2;
    const int* srcA = ei;
    const int* dstA = ei + E;

    char* ws = (char*)d_ws;
    size_t off = 0;
    auto alloc = [&](size_t bytes) {
        void* p = ws + off;
        off = (off + bytes + 255) & ~(size_t)255;
        return p;
    };
    int*      degi      = (int*)alloc((size_t)N * 4);
    float*    dis       = (float*)alloc((size_t)N * 4);
    int*      row_start = (int*)alloc((size_t)(N + 1) * 4);
    int*      bsums     = (int*)alloc(512 * 4);
    int*      csr_src   = (int*)alloc((size_t)E * 4);
    ushort_t* bufA      = (ushort_t*)alloc((size_t)N * 128 * 2);
    ushort_t* bufB      = (ushort_t*)alloc((size_t)N * 128 * 2);
    float*    C4        = (float*)alloc((size_t)N * 2 * 4);
    ushort_t* Wt1       = (ushort_t*)alloc((size_t)128 * 256 * 2);
    ushort_t* Wt2       = (ushort_t*)alloc((size_t)128 * 128 * 2);
    ushort_t* Wt3       = (ushort_t*)alloc((size_t)64 * 128 * 2);
    (void)ws_size;

    hipMemsetAsync(degi, 0, (size_t)N * 4, stream);

    // graph prep
    deg_count_kernel<<<(E + 255) / 256, 256, 0, stream>>>(dstA, degi, E);
    dis_kernel<<<(N + 255) / 256, 256, 0, stream>>>(degi, dis, N);
    const int nb = (N + 1023) >> 10;
    scan_block_kernel<<<nb, 1024, 0, stream>>>(degi, row_start, bsums, N);
    scan_sums_kernel<<<1, 128, 0, stream>>>(bsums, nb);
    scan_add_kernel<<<(N + 256) / 256, 256, 0, stream>>>(row_start, bsums, N, nb);
    scatter_kernel<<<(E + 255) / 256, 256, 0, stream>>>(srcA, dstA, row_start, degi,
                                                        csr_src, E);

    // weight transposes (bf16, padded)
    wt_kernel<<<(256 * 128 + 255) / 256, 256, 0, stream>>>(W1, Wt1, 256, 128, 256, 128);
    wt_kernel<<<(128 * 128 + 255) / 256, 256, 0, stream>>>(W2, Wt2, 128, 100, 128, 128);
    wt_kernel<<<(128 * 64 + 255) / 256, 256, 0, stream>>>(W3, Wt3, 100, 32, 128, 64);

    const int gx = (N + 127) / 128;
    const int aggBlocks128 = (N + 3) / 4;    // 4 waves/block, 1 node/wave
    const int aggBlocks32  = (N + 15) / 16;  // 16 nodes/block

    // layer 1: 256 -> 128 (A is fp32 x, converted during staging)
    mfma_gemm<true><<<dim3(gx, 2), 256, 0, stream>>>(x, Wt1, bufA, N, 256, 256, 256, 128, 128);
    aggregate128_kernel<128><<<aggBlocks128, 256, 0, stream>>>(
        bufA, row_start, csr_src, dis, b1, bufB, N);
    // layer 2: 128 -> 100 (padded to 128 with zeros)
    mfma_gemm<false><<<dim3(gx, 2), 256, 0, stream>>>(bufB, Wt2, bufA, N, 128, 128, 128, 128, 128);
    aggregate128_kernel<100><<<aggBlocks128, 256, 0, stream>>>(
        bufA, row_start, csr_src, dis, b2, bufB, N);
    // layer 3: 128(pad) -> 32
    mfma_gemm<false><<<dim3(gx, 1), 256, 0, stream>>>(bufB, Wt3, bufA, N, 128, 128, 128, 32, 32);
    aggregate32_kernel<<<aggBlocks32, 256, 0, stream>>>(
        bufA, row_start, csr_src, dis, b3, bufB, N);
    // layer 4: 32 -> 2, aggregate + softmax
    gemm32x2_kernel<<<(N + 255) / 256, 256, 0, stream>>>(bufB, W4, C4, N);
    aggregate2_softmax_kernel<<<(N + 255) / 256, 256, 0, stream>>>(
        C4, row_start, csr_src, dis, b4, (float*)d_out, N);
}

// Round 4
// 335.001 us; speedup vs baseline: 1.3702x; 1.3702x over previous
//
#include <hip/hip_runtime.h>
#include <math.h>

// ---------------------------------------------------------------------------
// GCN: 4x (bf16-MFMA GEMM -> symmetric-normalized aggregation (+bias, lrelu))
//      -> softmax.
// Graph prep per call (bucketed, LDS-local):
//   bin edges by dst>>8 -> per-bucket degree count -> rsqrt -> scan ->
//   per-bucket CSR build in LDS (coalesced csr writes).
// norm never materialized: out[n] = dis[n]*(sum_e dis[s]*h[s] + dis[n]*h[n]).
// ---------------------------------------------------------------------------

typedef unsigned short ushort_t;
typedef unsigned int   uint_t;
typedef short  bf16x8 __attribute__((ext_vector_type(8)));
typedef float  f32x4  __attribute__((ext_vector_type(4)));

#define BKT_SHIFT 8               // 256 nodes per bucket
#define BKT_CAP   5120            // >= max edges per bucket (mean 4096, ~16 sigma margin)
#define BIN_CHUNK 4096            // edges per bin workgroup

__device__ __forceinline__ ushort_t f2bf(float f) {
    union { float f; uint_t u; } v; v.f = f;
    uint_t u = v.u;
    u += 0x7fffu + ((u >> 16) & 1u);      // round-to-nearest-even
    return (ushort_t)(u >> 16);
}
__device__ __forceinline__ float bflo(uint_t u) {
    union { uint_t q; float f; } v; v.q = u << 16; return v.f;
}
__device__ __forceinline__ float bfhi(uint_t u) {
    union { uint_t q; float f; } v; v.q = u & 0xffff0000u; return v.f;
}

// ------------------------------- graph prep -------------------------------

// Pass 1: bin edges into per-bucket staging (uint2 = {src, dst}).
// Each workgroup reserves one contiguous run per bucket -> staging lines are
// single-workgroup-owned -> minimal writeback amplification.
__global__ __launch_bounds__(256) void bin_kernel(const int* __restrict__ srcArr,
                                                  const int* __restrict__ dstArr,
                                                  int* __restrict__ bkt_cursor,
                                                  uint2* __restrict__ staging,
                                                  int E, int nb) {
    __shared__ int hist[512];
    __shared__ int base[512];
    for (int b = threadIdx.x; b < 512; b += 256) hist[b] = 0;
    __syncthreads();
    const int e0 = blockIdx.x * BIN_CHUNK;
    #pragma unroll 4
    for (int k = 0; k < BIN_CHUNK / 256; ++k) {
        int e = e0 + k * 256 + threadIdx.x;
        if (e < E) atomicAdd(&hist[dstArr[e] >> BKT_SHIFT], 1);
    }
    __syncthreads();
    for (int b = threadIdx.x; b < nb; b += 256) {
        int h = hist[b];
        base[b] = h ? atomicAdd(&bkt_cursor[b], h) : 0;
    }
    __syncthreads();
    for (int b = threadIdx.x; b < 512; b += 256) hist[b] = 0;  // reuse as cursor
    __syncthreads();
    #pragma unroll 4
    for (int k = 0; k < BIN_CHUNK / 256; ++k) {
        int e = e0 + k * 256 + threadIdx.x;
        if (e < E) {
            int s = srcArr[e], d = dstArr[e];
            int b = d >> BKT_SHIFT;
            int p = atomicAdd(&hist[b], 1);
            int idx = base[b] + p;
            if (idx < BKT_CAP)
                staging[(size_t)b * BKT_CAP + idx] = make_uint2((uint_t)s, (uint_t)d);
        }
    }
}

// Pass 1.5: per-bucket degree count (LDS-local), coalesced degi writes.
__global__ __launch_bounds__(256) void deg_from_staging_kernel(const uint2* __restrict__ staging,
                                                               const int* __restrict__ bkt_cursor,
                                                               int* __restrict__ degi, int n) {
    __shared__ int cur[256];
    const int b  = blockIdx.x;
    const int lo = b << BKT_SHIFT;
    const int nl = min(256, n - lo);
    cur[threadIdx.x] = 0;
    __syncthreads();
    int cnt = min(bkt_cursor[b], BKT_CAP);
    for (int e = threadIdx.x; e < cnt; e += 256) {
        uint2 p = staging[(size_t)b * BKT_CAP + e];
        atomicAdd(&cur[(int)p.y - lo], 1);
    }
    __syncthreads();
    if ((int)threadIdx.x < nl) degi[lo + threadIdx.x] = cur[threadIdx.x];
}

__global__ void dis_kernel(const int* __restrict__ degi, float* __restrict__ dis, int n) {
    int i = blockIdx.x * blockDim.x + threadIdx.x;
    if (i < n) dis[i] = rsqrtf((float)(degi[i] + 1));  // +1 self-loop
}

// hierarchical exclusive scan: per-1024-block scan + block sums
__global__ void scan_block_kernel(const int* __restrict__ degi, int* __restrict__ row_excl,
                                  int* __restrict__ bsums, int n) {
    __shared__ int buf[1024];
    int i = blockIdx.x * 1024 + threadIdx.x;
    int v = (i < n) ? degi[i] : 0;
    buf[threadIdx.x] = v;
    __syncthreads();
    for (int off = 1; off < 1024; off <<= 1) {
        int t = (threadIdx.x >= (unsigned)off) ? buf[threadIdx.x - off] : 0;
        __syncthreads();
        buf[threadIdx.x] += t;
        __syncthreads();
    }
    if (i < n) row_excl[i] = buf[threadIdx.x] - v;
    if (threadIdx.x == 1023) bsums[blockIdx.x] = buf[1023];
}

__global__ void scan_sums_kernel(int* __restrict__ bsums, int nb) {
    __shared__ int buf[128];
    int v = ((int)threadIdx.x < nb) ? bsums[threadIdx.x] : 0;
    buf[threadIdx.x] = v;
    __syncthreads();
    for (int off = 1; off < 128; off <<= 1) {
        int t = (threadIdx.x >= (unsigned)off) ? buf[threadIdx.x - off] : 0;
        __syncthreads();
        buf[threadIdx.x] += t;
        __syncthreads();
    }
    if ((int)threadIdx.x < nb) bsums[threadIdx.x] = buf[threadIdx.x] - v;
    if (threadIdx.x == 0) bsums[nb] = buf[127];
}

__global__ void scan_add_kernel(int* __restrict__ row_start, const int* __restrict__ bsums,
                                int n, int nb) {
    int i = blockIdx.x * blockDim.x + threadIdx.x;
    if (i < n) row_start[i] += bsums[i >> 10];
    else if (i == n) row_start[n] = bsums[nb];
}

// Pass 2: build each bucket's CSR segment in LDS, flush coalesced.
__global__ __launch_bounds__(256) void csr_build_kernel(const uint2* __restrict__ staging,
                                                        const int* __restrict__ bkt_cursor,
                                                        const int* __restrict__ row_start,
                                                        int* __restrict__ csr_src, int n) {
    __shared__ int rs[257];
    __shared__ int cur[256];
    __shared__ int seg[BKT_CAP];
    const int b  = blockIdx.x;
    const int lo = b << BKT_SHIFT;
    const int nl = min(256, n - lo);
    if ((int)threadIdx.x <= nl) rs[threadIdx.x] = row_start[lo + threadIdx.x];
    cur[threadIdx.x] = 0;
    __syncthreads();
    const int sbase = rs[0];
    int cnt = min(bkt_cursor[b], BKT_CAP);
    for (int e = threadIdx.x; e < cnt; e += 256) {
        uint2 p = staging[(size_t)b * BKT_CAP + e];
        int ln = (int)p.y - lo;
        int q  = atomicAdd(&cur[ln], 1);
        seg[(rs[ln] - sbase) + q] = (int)p.x;
    }
    __syncthreads();
    for (int i = threadIdx.x; i < cnt; i += 256) csr_src[sbase + i] = seg[i];
}

// ------------------------------ dtype converts ----------------------------

// W [K x N] fp32 -> Wt [NP x KP] bf16 (transposed + zero-padded)
__global__ void wt_kernel(const float* __restrict__ W, ushort_t* __restrict__ Wt,
                          int K, int N, int KP, int NP) {
    int idx = blockIdx.x * blockDim.x + threadIdx.x;
    if (idx >= KP * NP) return;
    int n = idx / KP, k = idx % KP;
    float v = (k < K && n < N) ? W[(size_t)k * N + n] : 0.f;
    Wt[(size_t)n * KP + k] = f2bf(v);
}

// ------------------------------ MFMA GEMM ---------------------------------
// C[M x nstore] (bf16, stride ldc) = A[M x K] @ Bt[NP x K]^T (bf16, N-major)
// A is bf16 (lda stride) or fp32 (A_FP32: converted while staging to LDS).
// BM=128 BN=64 BK=64, 4 waves (2Mx2N), per-wave 64x32 out (4x2 frags).
template <bool A_FP32>
__global__ __launch_bounds__(256) void mfma_gemm(const void* __restrict__ Av,
                                                 const ushort_t* __restrict__ Bt,
                                                 ushort_t* __restrict__ C,
                                                 int M, int K, int lda, int ldb,
                                                 int ldc, int nstore) {
    __shared__ __attribute__((aligned(16))) ushort_t As[128][72];  // +8 pad
    __shared__ __attribute__((aligned(16))) ushort_t Bs[64][72];

    const int t    = threadIdx.x;
    const int lane = t & 63;
    const int w    = t >> 6;
    const int wm   = w >> 1, wn = w & 1;
    const int m0   = blockIdx.x * 128;
    const int n0   = blockIdx.y * 64;

    f32x4 acc[4][2];
    #pragma unroll
    for (int mi = 0; mi < 4; ++mi)
        #pragma unroll
        for (int ni = 0; ni < 2; ++ni) acc[mi][ni] = (f32x4){0.f, 0.f, 0.f, 0.f};

    const int srow = t >> 3;          // 0..31
    const int scol = (t & 7) * 8;     // 0..56

    for (int k0 = 0; k0 < K; k0 += 64) {
        #pragma unroll
        for (int it = 0; it < 4; ++it) {            // A tile 128x64
            int r = srow + it * 32;
            int gm = m0 + r;
            bf16x8 v = {0, 0, 0, 0, 0, 0, 0, 0};
            if (gm < M) {
                if (A_FP32) {
                    const float* A = (const float*)Av;
                    const float4 f0 = *(const float4*)(A + (size_t)gm * lda + k0 + scol);
                    const float4 f1 = *(const float4*)(A + (size_t)gm * lda + k0 + scol + 4);
                    ushort_t o[8] = { f2bf(f0.x), f2bf(f0.y), f2bf(f0.z), f2bf(f0.w),
                                      f2bf(f1.x), f2bf(f1.y), f2bf(f1.z), f2bf(f1.w) };
                    v = *(const bf16x8*)o;
                } else {
                    const ushort_t* A = (const ushort_t*)Av;
                    v = *(const bf16x8*)(A + (size_t)gm * lda + k0 + scol);
                }
            }
            *(bf16x8*)&As[r][scol] = v;
        }
        #pragma unroll
        for (int it = 0; it < 2; ++it) {            // B tile 64x64 (rows padded)
            int r = srow + it * 32;
            bf16x8 v = *(const bf16x8*)(Bt + (size_t)(n0 + r) * ldb + k0 + scol);
            *(bf16x8*)&Bs[r][scol] = v;
        }
        __syncthreads();
        #pragma unroll
        for (int kk = 0; kk < 2; ++kk) {
            bf16x8 af[4], bfr[2];
            const int kc = kk * 32 + (lane >> 4) * 8;
            #pragma unroll
            for (int mi = 0; mi < 4; ++mi)
                af[mi] = *(const bf16x8*)&As[wm * 64 + mi * 16 + (lane & 15)][kc];
            #pragma unroll
            for (int ni = 0; ni < 2; ++ni)
                bfr[ni] = *(const bf16x8*)&Bs[wn * 32 + ni * 16 + (lane & 15)][kc];
            #pragma unroll
            for (int mi = 0; mi < 4; ++mi)
                #pragma unroll
                for (int ni = 0; ni < 2; ++ni)
                    acc[mi][ni] = __builtin_amdgcn_mfma_f32_16x16x32_bf16(
                        af[mi], bfr[ni], acc[mi][ni], 0, 0, 0);
        }
        __syncthreads();
    }

    // C/D layout: col = lane&15, row = (lane>>4)*4 + r
    #pragma unroll
    for (int mi = 0; mi < 4; ++mi)
        #pragma unroll
        for (int ni = 0; ni < 2; ++ni)
            #pragma unroll
            for (int r = 0; r < 4; ++r) {
                int gm = m0 + wm * 64 + mi * 16 + (lane >> 4) * 4 + r;
                int gn = n0 + wn * 32 + ni * 16 + (lane & 15);
                if (gm < M && gn < nstore)
                    C[(size_t)gm * ldc + gn] = f2bf(acc[mi][ni][r]);
            }
}

// ---------------------------- aggregation ---------------------------------
// out[n] = lrelu( dn*( sum_e dis[s]*h[s] + dn*h[n] ) + bias )
// FPAD=128: one wave per node, lane holds features {2l, 2l+1}.
template <int F>
__global__ void aggregate128_kernel(const ushort_t* __restrict__ h, const int* __restrict__ row_start,
                                    const int* __restrict__ csr_src,
                                    const float* __restrict__ dis, const float* __restrict__ bias,
                                    ushort_t* __restrict__ out, int n) {
    int wid  = threadIdx.x >> 6;
    int lane = threadIdx.x & 63;
    int node = blockIdx.x * (blockDim.x >> 6) + wid;
    if (node >= n) return;
    const int f0 = 2 * lane, f1 = f0 + 1;
    float dn = dis[node];
    uint_t v = *(const uint_t*)(h + (size_t)node * 128 + f0);
    float acc0 = bflo(v) * dn;          // self-loop: dn*h[n]; total gets *dn below
    float acc1 = bfhi(v) * dn;
    int i = row_start[node], end = row_start[node + 1];
    for (; i + 4 <= end; i += 4) {
        int s0 = csr_src[i], s1 = csr_src[i + 1], s2 = csr_src[i + 2], s3 = csr_src[i + 3];
        float m0 = dis[s0], m1 = dis[s1], m2 = dis[s2], m3 = dis[s3];
        uint_t u0 = *(const uint_t*)(h + (size_t)s0 * 128 + f0);
        uint_t u1 = *(const uint_t*)(h + (size_t)s1 * 128 + f0);
        uint_t u2 = *(const uint_t*)(h + (size_t)s2 * 128 + f0);
        uint_t u3 = *(const uint_t*)(h + (size_t)s3 * 128 + f0);
        acc0 += bflo(u0) * m0; acc1 += bfhi(u0) * m0;
        acc0 += bflo(u1) * m1; acc1 += bfhi(u1) * m1;
        acc0 += bflo(u2) * m2; acc1 += bfhi(u2) * m2;
        acc0 += bflo(u3) * m3; acc1 += bfhi(u3) * m3;
    }
    for (; i < end; ++i) {
        int s = csr_src[i];
        float nrm = dis[s];
        uint_t u = *(const uint_t*)(h + (size_t)s * 128 + f0);
        acc0 += bflo(u) * nrm; acc1 += bfhi(u) * nrm;
    }
    acc0 = acc0 * dn + ((f0 < F) ? bias[f0] : 0.f);
    acc1 = acc1 * dn + ((f1 < F) ? bias[f1] : 0.f);
    acc0 = (acc0 > 0.f) ? acc0 : 0.1f * acc0;
    acc1 = (acc1 > 0.f) ? acc1 : 0.1f * acc1;
    if (f0 >= F) acc0 = 0.f;   // keep K-padding exactly zero
    if (f1 >= F) acc1 = 0.f;
    uint_t o = (uint_t)f2bf(acc0) | ((uint_t)f2bf(acc1) << 16);
    *(uint_t*)(out + (size_t)node * 128 + f0) = o;
}

// F=32: 16-lane group per node (2 features per lane), 4 nodes per wave.
__global__ void aggregate32_kernel(const ushort_t* __restrict__ h, const int* __restrict__ row_start,
                                   const int* __restrict__ csr_src,
                                   const float* __restrict__ dis, const float* __restrict__ bias,
                                   ushort_t* __restrict__ out, int n) {
    int lane16 = threadIdx.x & 15;
    int node = blockIdx.x * (blockDim.x >> 4) + (threadIdx.x >> 4);
    if (node >= n) return;
    const int f0 = 2 * lane16;
    float dn = dis[node];
    uint_t v = *(const uint_t*)(h + (size_t)node * 32 + f0);
    float acc0 = bflo(v) * dn;
    float acc1 = bfhi(v) * dn;
    int i = row_start[node], end = row_start[node + 1];
    for (; i + 4 <= end; i += 4) {
        int s0 = csr_src[i], s1 = csr_src[i + 1], s2 = csr_src[i + 2], s3 = csr_src[i + 3];
        float m0 = dis[s0], m1 = dis[s1], m2 = dis[s2], m3 = dis[s3];
        uint_t u0 = *(const uint_t*)(h + (size_t)s0 * 32 + f0);
        uint_t u1 = *(const uint_t*)(h + (size_t)s1 * 32 + f0);
        uint_t u2 = *(const uint_t*)(h + (size_t)s2 * 32 + f0);
        uint_t u3 = *(const uint_t*)(h + (size_t)s3 * 32 + f0);
        acc0 += bflo(u0) * m0; acc1 += bfhi(u0) * m0;
        acc0 += bflo(u1) * m1; acc1 += bfhi(u1) * m1;
        acc0 += bflo(u2) * m2; acc1 += bfhi(u2) * m2;
        acc0 += bflo(u3) * m3; acc1 += bfhi(u3) * m3;
    }
    for (; i < end; ++i) {
        int s = csr_src[i];
        float nrm = dis[s];
        uint_t u = *(const uint_t*)(h + (size_t)s * 32 + f0);
        acc0 += bflo(u) * nrm; acc1 += bfhi(u) * nrm;
    }
    acc0 = acc0 * dn + bias[f0];
    acc1 = acc1 * dn + bias[f0 + 1];
    acc0 = (acc0 > 0.f) ? acc0 : 0.1f * acc0;
    acc1 = (acc1 > 0.f) ? acc1 : 0.1f * acc1;
    uint_t o = (uint_t)f2bf(acc0) | ((uint_t)f2bf(acc1) << 16);
    *(uint_t*)(out + (size_t)node * 32 + f0) = o;
}

// layer 4 GEMM: [N x 32] bf16 @ [32 x 2] fp32 -> fp32, one thread per node
__global__ void gemm32x2_kernel(const ushort_t* __restrict__ H, const float* __restrict__ W4,
                                float* __restrict__ C, int n) {
    int node = blockIdx.x * blockDim.x + threadIdx.x;
    if (node >= n) return;
    const uint_t* row = (const uint_t*)(H + (size_t)node * 32);
    float a0 = 0.f, a1 = 0.f;
    #pragma unroll
    for (int k2 = 0; k2 < 16; ++k2) {
        uint_t u = row[k2];
        float x0 = bflo(u), x1 = bfhi(u);
        int k = 2 * k2;
        a0 += x0 * W4[k * 2]     + x1 * W4[(k + 1) * 2];
        a1 += x0 * W4[k * 2 + 1] + x1 * W4[(k + 1) * 2 + 1];
    }
    C[2 * (size_t)node] = a0;
    C[2 * (size_t)node + 1] = a1;
}

// final aggregation (F=2) + bias + softmax, one thread per node
__global__ void aggregate2_softmax_kernel(const float* __restrict__ h, const int* __restrict__ row_start,
                                          const int* __restrict__ csr_src,
                                          const float* __restrict__ dis, const float* __restrict__ bias,
                                          float* __restrict__ out, int n) {
    int node = blockIdx.x * blockDim.x + threadIdx.x;
    if (node >= n) return;
    float dn = dis[node];
    float a0 = h[2 * (size_t)node]     * dn;
    float a1 = h[2 * (size_t)node + 1] * dn;
    int beg = row_start[node], end = row_start[node + 1];
    for (int i = beg; i < end; ++i) {
        int s = csr_src[i];
        float nrm = dis[s];
        a0 += h[2 * (size_t)s]     * nrm;
        a1 += h[2 * (size_t)s + 1] * nrm;
    }
    a0 = a0 * dn + bias[0];
    a1 = a1 * dn + bias[1];
    float m  = fmaxf(a0, a1);
    float e0 = expf(a0 - m), e1 = expf(a1 - m);
    float inv = 1.f / (e0 + e1);
    out[2 * (size_t)node]     = e0 * inv;
    out[2 * (size_t)node + 1] = e1 * inv;
}

// ---------------------------------------------------------------------------

extern "C" void kernel_launch(void* const* d_in, const int* in_sizes, int n_in,
                              void* d_out, int out_size, void* d_ws, size_t ws_size,
                              hipStream_t stream) {
    const float* x  = (const float*)d_in[0];
    const int*   ei = (const int*)d_in[1];
    const float* W1 = (const float*)d_in[2];
    const float* b1 = (const float*)d_in[3];
    const float* W2 = (const float*)d_in[4];
    const float* b2 = (const float*)d_in[5];
    const float* W3 = (const float*)d_in[6];
    const float* b3 = (const float*)d_in[7];
    const float* W4 = (const float*)d_in[8];
    const float* b4 = (const float*)d_in[9];

    const int N = in_sizes[0] / 256;
    const int E = in_sizes[1] / 2;
    const int* srcA = ei;
    const int* dstA = ei + E;
    const int nbkt = (N + 255) >> BKT_SHIFT;   // buckets of 256 nodes

    char* ws = (char*)d_ws;
    size_t off = 0;
    auto alloc = [&](size_t bytes) {
        void* p = ws + off;
        off = (off + bytes + 255) & ~(size_t)255;
        return p;
    };
    int*      degi       = (int*)alloc((size_t)N * 4);
    float*    dis        = (float*)alloc((size_t)N * 4);
    int*      row_start  = (int*)alloc((size_t)(N + 1) * 4);
    int*      bsums      = (int*)alloc(512 * 4);
    int*      bkt_cursor = (int*)alloc((size_t)nbkt * 4);
    int*      csr_src    = (int*)alloc((size_t)E * 4);
    uint2*    staging    = (uint2*)alloc((size_t)nbkt * BKT_CAP * 8);
    ushort_t* bufA       = (ushort_t*)alloc((size_t)N * 128 * 2);
    ushort_t* bufB       = (ushort_t*)alloc((size_t)N * 128 * 2);
    float*    C4         = (float*)alloc((size_t)N * 2 * 4);
    ushort_t* Wt1        = (ushort_t*)alloc((size_t)128 * 256 * 2);
    ushort_t* Wt2        = (ushort_t*)alloc((size_t)128 * 128 * 2);
    ushort_t* Wt3        = (ushort_t*)alloc((size_t)64 * 128 * 2);
    (void)ws_size;

    hipMemsetAsync(bkt_cursor, 0, (size_t)nbkt * 4, stream);

    // graph prep (bucketed)
    bin_kernel<<<(E + BIN_CHUNK - 1) / BIN_CHUNK, 256, 0, stream>>>(
        srcA, dstA, bkt_cursor, staging, E, nbkt);
    deg_from_staging_kernel<<<nbkt, 256, 0, stream>>>(staging, bkt_cursor, degi, N);
    dis_kernel<<<(N + 255) / 256, 256, 0, stream>>>(degi, dis, N);
    const int nb = (N + 1023) >> 10;
    scan_block_kernel<<<nb, 1024, 0, stream>>>(degi, row_start, bsums, N);
    scan_sums_kernel<<<1, 128, 0, stream>>>(bsums, nb);
    scan_add_kernel<<<(N + 256) / 256, 256, 0, stream>>>(row_start, bsums, N, nb);
    csr_build_kernel<<<nbkt, 256, 0, stream>>>(staging, bkt_cursor, row_start, csr_src, N);

    // weight transposes (bf16, padded)
    wt_kernel<<<(256 * 128 + 255) / 256, 256, 0, stream>>>(W1, Wt1, 256, 128, 256, 128);
    wt_kernel<<<(128 * 128 + 255) / 256, 256, 0, stream>>>(W2, Wt2, 128, 100, 128, 128);
    wt_kernel<<<(128 * 64 + 255) / 256, 256, 0, stream>>>(W3, Wt3, 100, 32, 128, 64);

    const int gx = (N + 127) / 128;
    const int aggBlocks128 = (N + 3) / 4;    // 4 waves/block, 1 node/wave
    const int aggBlocks32  = (N + 15) / 16;  // 16 nodes/block

    // layer 1: 256 -> 128 (A is fp32 x, converted during staging)
    mfma_gemm<true><<<dim3(gx, 2), 256, 0, stream>>>(x, Wt1, bufA, N, 256, 256, 256, 128, 128);
    aggregate128_kernel<128><<<aggBlocks128, 256, 0, stream>>>(
        bufA, row_start, csr_src, dis, b1, bufB, N);
    // layer 2: 128 -> 100 (padded to 128 with zeros)
    mfma_gemm<false><<<dim3(gx, 2), 256, 0, stream>>>(bufB, Wt2, bufA, N, 128, 128, 128, 128, 128);
    aggregate128_kernel<100><<<aggBlocks128, 256, 0, stream>>>(
        bufA, row_start, csr_src, dis, b2, bufB, N);
    // layer 3: 128(pad) -> 32
    mfma_gemm<false><<<dim3(gx, 1), 256, 0, stream>>>(bufB, Wt3, bufA, N, 128, 128, 128, 32, 32);
    aggregate32_kernel<<<aggBlocks32, 256, 0, stream>>>(
        bufA, row_start, csr_src, dis, b3, bufB, N);
    // layer 4: 32 -> 2, aggregate + softmax
    gemm32x2_kernel<<<(N + 255) / 256, 256, 0, stream>>>(bufB, W4, C4, N);
    aggregate2_softmax_kernel<<<(N + 255) / 256, 256, 0, stream>>>(
        C4, row_start, csr_src, dis, b4, (float*)d_out, N);
}

// Round 5
// 321.509 us; speedup vs baseline: 1.4277x; 1.0420x over previous
//
#include <hip/hip_runtime.h>
#include <math.h>

// ---------------------------------------------------------------------------
// GCN: 4x (bf16-MFMA GEMM (epilogue pre-scales rows by dis) ->
//          pure-sum aggregation (+bias, lrelu)) -> softmax.
// Graph prep per call (bucketed, LDS-local):
//   bin edges by dst>>8 -> per-bucket degree+dis -> scan -> bucket CSR in LDS.
// out[n] = dis[n]*( sum_e h'[s] + h'[n] ) + b,  h'[r] = dis[r]*(h@W)[r]
// ---------------------------------------------------------------------------

typedef unsigned short ushort_t;
typedef unsigned int   uint_t;
typedef short  bf16x8 __attribute__((ext_vector_type(8)));
typedef float  f32x4  __attribute__((ext_vector_type(4)));

#define BKT_SHIFT 8               // 256 nodes per bucket
#define BKT_CAP   5120            // >= max edges per bucket (mean 4096, +16 sigma)
#define BIN_CHUNK 4096            // edges per bin workgroup

__device__ __forceinline__ ushort_t f2bf(float f) {
    union { float f; uint_t u; } v; v.f = f;
    uint_t u = v.u;
    u += 0x7fffu + ((u >> 16) & 1u);      // round-to-nearest-even
    return (ushort_t)(u >> 16);
}
__device__ __forceinline__ float bflo(uint_t u) {
    union { uint_t q; float f; } v; v.q = u << 16; return v.f;
}
__device__ __forceinline__ float bfhi(uint_t u) {
    union { uint_t q; float f; } v; v.q = u & 0xffff0000u; return v.f;
}

// ------------------------------- graph prep -------------------------------

__global__ __launch_bounds__(256) void bin_kernel(const int* __restrict__ srcArr,
                                                  const int* __restrict__ dstArr,
                                                  int* __restrict__ bkt_cursor,
                                                  uint2* __restrict__ staging,
                                                  int E, int nb) {
    __shared__ int hist[512];
    __shared__ int base[512];
    for (int b = threadIdx.x; b < 512; b += 256) hist[b] = 0;
    __syncthreads();
    const int e0 = blockIdx.x * BIN_CHUNK;
    #pragma unroll 4
    for (int k = 0; k < BIN_CHUNK / 256; ++k) {
        int e = e0 + k * 256 + threadIdx.x;
        if (e < E) atomicAdd(&hist[dstArr[e] >> BKT_SHIFT], 1);
    }
    __syncthreads();
    for (int b = threadIdx.x; b < nb; b += 256) {
        int h = hist[b];
        base[b] = h ? atomicAdd(&bkt_cursor[b], h) : 0;
    }
    __syncthreads();
    for (int b = threadIdx.x; b < 512; b += 256) hist[b] = 0;  // reuse as cursor
    __syncthreads();
    #pragma unroll 4
    for (int k = 0; k < BIN_CHUNK / 256; ++k) {
        int e = e0 + k * 256 + threadIdx.x;
        if (e < E) {
            int s = srcArr[e], d = dstArr[e];
            int b = d >> BKT_SHIFT;
            int p = atomicAdd(&hist[b], 1);
            int idx = base[b] + p;
            if (idx < BKT_CAP)
                staging[(size_t)b * BKT_CAP + idx] = make_uint2((uint_t)s, (uint_t)d);
        }
    }
}

// per-bucket degree count (LDS-local) + dis = rsqrt(deg+1), coalesced writes
__global__ __launch_bounds__(256) void deg_from_staging_kernel(const uint2* __restrict__ staging,
                                                               const int* __restrict__ bkt_cursor,
                                                               int* __restrict__ degi,
                                                               float* __restrict__ dis, int n) {
    __shared__ int cur[256];
    const int b  = blockIdx.x;
    const int lo = b << BKT_SHIFT;
    const int nl = min(256, n - lo);
    cur[threadIdx.x] = 0;
    __syncthreads();
    int cnt = min(bkt_cursor[b], BKT_CAP);
    for (int e = threadIdx.x; e < cnt; e += 256) {
        uint2 p = staging[(size_t)b * BKT_CAP + e];
        atomicAdd(&cur[(int)p.y - lo], 1);
    }
    __syncthreads();
    if ((int)threadIdx.x < nl) {
        int d = cur[threadIdx.x];
        degi[lo + threadIdx.x] = d;
        dis[lo + threadIdx.x] = rsqrtf((float)(d + 1));
    }
}

// hierarchical exclusive scan
__global__ void scan_block_kernel(const int* __restrict__ degi, int* __restrict__ row_excl,
                                  int* __restrict__ bsums, int n) {
    __shared__ int buf[1024];
    int i = blockIdx.x * 1024 + threadIdx.x;
    int v = (i < n) ? degi[i] : 0;
    buf[threadIdx.x] = v;
    __syncthreads();
    for (int off = 1; off < 1024; off <<= 1) {
        int t = (threadIdx.x >= (unsigned)off) ? buf[threadIdx.x - off] : 0;
        __syncthreads();
        buf[threadIdx.x] += t;
        __syncthreads();
    }
    if (i < n) row_excl[i] = buf[threadIdx.x] - v;
    if (threadIdx.x == 1023) bsums[blockIdx.x] = buf[1023];
}

__global__ void scan_sums_kernel(int* __restrict__ bsums, int nb) {
    __shared__ int buf[128];
    int v = ((int)threadIdx.x < nb) ? bsums[threadIdx.x] : 0;
    buf[threadIdx.x] = v;
    __syncthreads();
    for (int off = 1; off < 128; off <<= 1) {
        int t = (threadIdx.x >= (unsigned)off) ? buf[threadIdx.x - off] : 0;
        __syncthreads();
        buf[threadIdx.x] += t;
        __syncthreads();
    }
    if ((int)threadIdx.x < nb) bsums[threadIdx.x] = buf[threadIdx.x] - v;
    if (threadIdx.x == 0) bsums[nb] = buf[127];
}

__global__ void scan_add_kernel(int* __restrict__ row_start, const int* __restrict__ bsums,
                                int n, int nb) {
    int i = blockIdx.x * blockDim.x + threadIdx.x;
    if (i < n) row_start[i] += bsums[i >> 10];
    else if (i == n) row_start[n] = bsums[nb];
}

// build each bucket's CSR segment in LDS, flush coalesced
__global__ __launch_bounds__(256) void csr_build_kernel(const uint2* __restrict__ staging,
                                                        const int* __restrict__ bkt_cursor,
                                                        const int* __restrict__ row_start,
                                                        int* __restrict__ csr_src, int n) {
    __shared__ int rs[257];
    __shared__ int cur[256];
    __shared__ int seg[BKT_CAP];
    const int b  = blockIdx.x;
    const int lo = b << BKT_SHIFT;
    const int nl = min(256, n - lo);
    if ((int)threadIdx.x <= nl) rs[threadIdx.x] = row_start[lo + threadIdx.x];
    cur[threadIdx.x] = 0;
    __syncthreads();
    const int sbase = rs[0];
    int cnt = min(bkt_cursor[b], BKT_CAP);
    for (int e = threadIdx.x; e < cnt; e += 256) {
        uint2 p = staging[(size_t)b * BKT_CAP + e];
        int ln = (int)p.y - lo;
        int q  = atomicAdd(&cur[ln], 1);
        seg[(rs[ln] - sbase) + q] = (int)p.x;
    }
    __syncthreads();
    for (int i = threadIdx.x; i < cnt; i += 256) csr_src[sbase + i] = seg[i];
}

// -------------------- weight transposes (one kernel) -----------------------
// Wt1: [128n x 256k] <- W1[256x128]; Wt2: [128n x 128k] <- W2[128x100] pad;
// Wt3: [64n x 128k] <- W3[100x32] pad.
__global__ void wt_all_kernel(const float* __restrict__ W1, const float* __restrict__ W2,
                              const float* __restrict__ W3,
                              ushort_t* __restrict__ Wt1, ushort_t* __restrict__ Wt2,
                              ushort_t* __restrict__ Wt3) {
    int idx = blockIdx.x * blockDim.x + threadIdx.x;
    if (idx < 32768) {
        int nn = idx >> 8, k = idx & 255;
        Wt1[idx] = f2bf(W1[(size_t)k * 128 + nn]);
    } else if (idx < 49152) {
        int j = idx - 32768;
        int nn = j >> 7, k = j & 127;
        float v = (nn < 100) ? W2[(size_t)k * 100 + nn] : 0.f;
        Wt2[j] = f2bf(v);
    } else if (idx < 57344) {
        int j = idx - 49152;
        int nn = j >> 7, k = j & 127;
        float v = (k < 100 && nn < 32) ? W3[(size_t)k * 32 + nn] : 0.f;
        Wt3[j] = f2bf(v);
    }
}

// ------------------------------ MFMA GEMM ---------------------------------
// C[M x nstore] (bf16) = dis[row] * (A[M x K] @ Bt[NP x K]^T), row-pre-scaled.
template <bool A_FP32>
__global__ __launch_bounds__(256) void mfma_gemm(const void* __restrict__ Av,
                                                 const ushort_t* __restrict__ Bt,
                                                 ushort_t* __restrict__ C,
                                                 const float* __restrict__ dis,
                                                 int M, int K, int lda, int ldb,
                                                 int ldc, int nstore) {
    __shared__ __attribute__((aligned(16))) ushort_t As[128][72];  // +8 pad
    __shared__ __attribute__((aligned(16))) ushort_t Bs[64][72];

    const int t    = threadIdx.x;
    const int lane = t & 63;
    const int w    = t >> 6;
    const int wm   = w >> 1, wn = w & 1;
    const int m0   = blockIdx.x * 128;
    const int n0   = blockIdx.y * 64;

    f32x4 acc[4][2];
    #pragma unroll
    for (int mi = 0; mi < 4; ++mi)
        #pragma unroll
        for (int ni = 0; ni < 2; ++ni) acc[mi][ni] = (f32x4){0.f, 0.f, 0.f, 0.f};

    const int srow = t >> 3;          // 0..31
    const int scol = (t & 7) * 8;     // 0..56

    for (int k0 = 0; k0 < K; k0 += 64) {
        #pragma unroll
        for (int it = 0; it < 4; ++it) {            // A tile 128x64
            int r = srow + it * 32;
            int gm = m0 + r;
            bf16x8 v = {0, 0, 0, 0, 0, 0, 0, 0};
            if (gm < M) {
                if (A_FP32) {
                    const float* A = (const float*)Av;
                    const float4 f0 = *(const float4*)(A + (size_t)gm * lda + k0 + scol);
                    const float4 f1 = *(const float4*)(A + (size_t)gm * lda + k0 + scol + 4);
                    ushort_t o[8] = { f2bf(f0.x), f2bf(f0.y), f2bf(f0.z), f2bf(f0.w),
                                      f2bf(f1.x), f2bf(f1.y), f2bf(f1.z), f2bf(f1.w) };
                    v = *(const bf16x8*)o;
                } else {
                    const ushort_t* A = (const ushort_t*)Av;
                    v = *(const bf16x8*)(A + (size_t)gm * lda + k0 + scol);
                }
            }
            *(bf16x8*)&As[r][scol] = v;
        }
        #pragma unroll
        for (int it = 0; it < 2; ++it) {            // B tile 64x64
            int r = srow + it * 32;
            bf16x8 v = *(const bf16x8*)(Bt + (size_t)(n0 + r) * ldb + k0 + scol);
            *(bf16x8*)&Bs[r][scol] = v;
        }
        __syncthreads();
        #pragma unroll
        for (int kk = 0; kk < 2; ++kk) {
            bf16x8 af[4], bfr[2];
            const int kc = kk * 32 + (lane >> 4) * 8;
            #pragma unroll
            for (int mi = 0; mi < 4; ++mi)
                af[mi] = *(const bf16x8*)&As[wm * 64 + mi * 16 + (lane & 15)][kc];
            #pragma unroll
            for (int ni = 0; ni < 2; ++ni)
                bfr[ni] = *(const bf16x8*)&Bs[wn * 32 + ni * 16 + (lane & 15)][kc];
            #pragma unroll
            for (int mi = 0; mi < 4; ++mi)
                #pragma unroll
                for (int ni = 0; ni < 2; ++ni)
                    acc[mi][ni] = __builtin_amdgcn_mfma_f32_16x16x32_bf16(
                        af[mi], bfr[ni], acc[mi][ni], 0, 0, 0);
        }
        __syncthreads();
    }

    // C/D layout: col = lane&15, row = (lane>>4)*4 + r; pre-scale by dis[row]
    #pragma unroll
    for (int mi = 0; mi < 4; ++mi)
        #pragma unroll
        for (int r = 0; r < 4; ++r) {
            int gm = m0 + wm * 64 + mi * 16 + (lane >> 4) * 4 + r;
            if (gm >= M) continue;
            float d = dis[gm];
            #pragma unroll
            for (int ni = 0; ni < 2; ++ni) {
                int gn = n0 + wn * 32 + ni * 16 + (lane & 15);
                if (gn < nstore)
                    C[(size_t)gm * ldc + gn] = f2bf(acc[mi][ni][r] * d);
            }
        }
}

// ---------------------------- aggregation ---------------------------------
// h rows are pre-scaled (h' = dis*h). One wave per node; lanes 0-31 take even
// edges, 32-63 odd edges; each lane covers 4 features f = (lane&31)*4..+3 via
// one uint2 (4 bf16). Cross-half __shfl_xor(32) merge at the end.
template <int F>
__global__ void aggregate128_kernel(const ushort_t* __restrict__ h, const int* __restrict__ row_start,
                                    const int* __restrict__ csr_src,
                                    const float* __restrict__ dis, const float* __restrict__ bias,
                                    ushort_t* __restrict__ out, int n) {
    int wid  = threadIdx.x >> 6;
    int lane = threadIdx.x & 63;
    int node = blockIdx.x * (blockDim.x >> 6) + wid;
    if (node >= n) return;
    const int half = lane >> 5;
    const int fb   = (lane & 31) * 4;       // feature base (x4 per lane)
    float a0 = 0.f, a1 = 0.f, a2 = 0.f, a3 = 0.f;
    int i = row_start[node], end = row_start[node + 1];
    const int cnt = end - i;
    // 4 pairs (8 edges) per iteration
    for (; i + 8 <= end; i += 8) {
        int s0 = csr_src[i     + half];
        int s1 = csr_src[i + 2 + half];
        int s2 = csr_src[i + 4 + half];
        int s3 = csr_src[i + 6 + half];
        uint2 u0 = *(const uint2*)(h + (size_t)s0 * 128 + fb);
        uint2 u1 = *(const uint2*)(h + (size_t)s1 * 128 + fb);
        uint2 u2 = *(const uint2*)(h + (size_t)s2 * 128 + fb);
        uint2 u3 = *(const uint2*)(h + (size_t)s3 * 128 + fb);
        a0 += bflo(u0.x); a1 += bfhi(u0.x); a2 += bflo(u0.y); a3 += bfhi(u0.y);
        a0 += bflo(u1.x); a1 += bfhi(u1.x); a2 += bflo(u1.y); a3 += bfhi(u1.y);
        a0 += bflo(u2.x); a1 += bfhi(u2.x); a2 += bflo(u2.y); a3 += bfhi(u2.y);
        a0 += bflo(u3.x); a1 += bfhi(u3.x); a2 += bflo(u3.y); a3 += bfhi(u3.y);
    }
    for (; i + 2 <= end; i += 2) {
        int s = csr_src[i + half];
        uint2 u = *(const uint2*)(h + (size_t)s * 128 + fb);
        a0 += bflo(u.x); a1 += bfhi(u.x); a2 += bflo(u.y); a3 += bfhi(u.y);
    }
    if ((cnt & 1) && half == 0) {           // tail edge on lower half only
        int s = csr_src[end - 1];
        uint2 u = *(const uint2*)(h + (size_t)s * 128 + fb);
        a0 += bflo(u.x); a1 += bfhi(u.x); a2 += bflo(u.y); a3 += bfhi(u.y);
    }
    // merge halves (width 64 shuffle)
    a0 += __shfl_xor(a0, 32);
    a1 += __shfl_xor(a1, 32);
    a2 += __shfl_xor(a2, 32);
    a3 += __shfl_xor(a3, 32);
    if (half == 0) {
        // self-loop (h' already = dis*h)
        uint2 u = *(const uint2*)(h + (size_t)node * 128 + fb);
        a0 += bflo(u.x); a1 += bfhi(u.x); a2 += bflo(u.y); a3 += bfhi(u.y);
        float dn = dis[node];
        float b0 = 0.f, b1 = 0.f, b2 = 0.f, b3 = 0.f;
        if (fb < F) { float4 bv = *(const float4*)(bias + fb); b0 = bv.x; b1 = bv.y; b2 = bv.z; b3 = bv.w; }
        a0 = a0 * dn + b0;  a1 = a1 * dn + b1;
        a2 = a2 * dn + b2;  a3 = a3 * dn + b3;
        a0 = (a0 > 0.f) ? a0 : 0.1f * a0;
        a1 = (a1 > 0.f) ? a1 : 0.1f * a1;
        a2 = (a2 > 0.f) ? a2 : 0.1f * a2;
        a3 = (a3 > 0.f) ? a3 : 0.1f * a3;
        if (fb >= F) { a0 = 0.f; a1 = 0.f; a2 = 0.f; a3 = 0.f; }  // keep padding zero
        uint2 o;
        o.x = (uint_t)f2bf(a0) | ((uint_t)f2bf(a1) << 16);
        o.y = (uint_t)f2bf(a2) | ((uint_t)f2bf(a3) << 16);
        *(uint2*)(out + (size_t)node * 128 + fb) = o;
    }
}

// F=32, h pre-scaled: 16-lane group per node (2 features/lane), 4 nodes/wave
__global__ void aggregate32_kernel(const ushort_t* __restrict__ h, const int* __restrict__ row_start,
                                   const int* __restrict__ csr_src,
                                   const float* __restrict__ dis, const float* __restrict__ bias,
                                   ushort_t* __restrict__ out, int n) {
    int lane16 = threadIdx.x & 15;
    int node = blockIdx.x * (blockDim.x >> 4) + (threadIdx.x >> 4);
    if (node >= n) return;
    const int f0 = 2 * lane16;
    uint_t v = *(const uint_t*)(h + (size_t)node * 32 + f0);
    float acc0 = bflo(v);               // self-loop (pre-scaled)
    float acc1 = bfhi(v);
    int i = row_start[node], end = row_start[node + 1];
    for (; i + 4 <= end; i += 4) {
        int s0 = csr_src[i], s1 = csr_src[i + 1], s2 = csr_src[i + 2], s3 = csr_src[i + 3];
        uint_t u0 = *(const uint_t*)(h + (size_t)s0 * 32 + f0);
        uint_t u1 = *(const uint_t*)(h + (size_t)s1 * 32 + f0);
        uint_t u2 = *(const uint_t*)(h + (size_t)s2 * 32 + f0);
        uint_t u3 = *(const uint_t*)(h + (size_t)s3 * 32 + f0);
        acc0 += bflo(u0) + bflo(u1) + bflo(u2) + bflo(u3);
        acc1 += bfhi(u0) + bfhi(u1) + bfhi(u2) + bfhi(u3);
    }
    for (; i < end; ++i) {
        int s = csr_src[i];
        uint_t u = *(const uint_t*)(h + (size_t)s * 32 + f0);
        acc0 += bflo(u); acc1 += bfhi(u);
    }
    float dn = dis[node];
    acc0 = acc0 * dn + bias[f0];
    acc1 = acc1 * dn + bias[f0 + 1];
    acc0 = (acc0 > 0.f) ? acc0 : 0.1f * acc0;
    acc1 = (acc1 > 0.f) ? acc1 : 0.1f * acc1;
    uint_t o = (uint_t)f2bf(acc0) | ((uint_t)f2bf(acc1) << 16);
    *(uint_t*)(out + (size_t)node * 32 + f0) = o;
}

// layer 4 GEMM: [N x 32] bf16 @ [32 x 2] fp32 -> fp32, pre-scaled by dis[node]
__global__ void gemm32x2_kernel(const ushort_t* __restrict__ H, const float* __restrict__ W4,
                                const float* __restrict__ dis, float* __restrict__ C, int n) {
    int node = blockIdx.x * blockDim.x + threadIdx.x;
    if (node >= n) return;
    const uint_t* row = (const uint_t*)(H + (size_t)node * 32);
    float a0 = 0.f, a1 = 0.f;
    #pragma unroll
    for (int k2 = 0; k2 < 16; ++k2) {
        uint_t u = row[k2];
        float x0 = bflo(u), x1 = bfhi(u);
        int k = 2 * k2;
        a0 += x0 * W4[k * 2]     + x1 * W4[(k + 1) * 2];
        a1 += x0 * W4[k * 2 + 1] + x1 * W4[(k + 1) * 2 + 1];
    }
    float d = dis[node];
    C[2 * (size_t)node]     = a0 * d;
    C[2 * (size_t)node + 1] = a1 * d;
}

// final aggregation (F=2, h pre-scaled) + bias + softmax, one thread per node
__global__ void aggregate2_softmax_kernel(const float* __restrict__ h, const int* __restrict__ row_start,
                                          const int* __restrict__ csr_src,
                                          const float* __restrict__ dis, const float* __restrict__ bias,
                                          float* __restrict__ out, int n) {
    int node = blockIdx.x * blockDim.x + threadIdx.x;
    if (node >= n) return;
    float a0 = h[2 * (size_t)node];
    float a1 = h[2 * (size_t)node + 1];
    int beg = row_start[node], end = row_start[node + 1];
    for (int i = beg; i < end; ++i) {
        int s = csr_src[i];
        a0 += h[2 * (size_t)s];
        a1 += h[2 * (size_t)s + 1];
    }
    float dn = dis[node];
    a0 = a0 * dn + bias[0];
    a1 = a1 * dn + bias[1];
    float m  = fmaxf(a0, a1);
    float e0 = expf(a0 - m), e1 = expf(a1 - m);
    float inv = 1.f / (e0 + e1);
    out[2 * (size_t)node]     = e0 * inv;
    out[2 * (size_t)node + 1] = e1 * inv;
}

// ---------------------------------------------------------------------------

extern "C" void kernel_launch(void* const* d_in, const int* in_sizes, int n_in,
                              void* d_out, int out_size, void* d_ws, size_t ws_size,
                              hipStream_t stream) {
    const float* x  = (const float*)d_in[0];
    const int*   ei = (const int*)d_in[1];
    const float* W1 = (const float*)d_in[2];
    const float* b1 = (const float*)d_in[3];
    const float* W2 = (const float*)d_in[4];
    const float* b2 = (const float*)d_in[5];
    const float* W3 = (const float*)d_in[6];
    const float* b3 = (const float*)d_in[7];
    const float* W4 = (const float*)d_in[8];
    const float* b4 = (const float*)d_in[9];

    const int N = in_sizes[0] / 256;
    const int E = in_sizes[1] / 2;
    const int* srcA = ei;
    const int* dstA = ei + E;
    const int nbkt = (N + 255) >> BKT_SHIFT;

    char* ws = (char*)d_ws;
    size_t off = 0;
    auto alloc = [&](size_t bytes) {
        void* p = ws + off;
        off = (off + bytes + 255) & ~(size_t)255;
        return p;
    };
    int*      degi       = (int*)alloc((size_t)N * 4);
    float*    dis        = (float*)alloc((size_t)N * 4);
    int*      row_start  = (int*)alloc((size_t)(N + 1) * 4);
    int*      bsums      = (int*)alloc(512 * 4);
    int*      bkt_cursor = (int*)alloc((size_t)nbkt * 4);
    int*      csr_src    = (int*)alloc((size_t)E * 4);
    uint2*    staging    = (uint2*)alloc((size_t)nbkt * BKT_CAP * 8);
    ushort_t* bufA       = (ushort_t*)alloc((size_t)N * 128 * 2);
    ushort_t* bufB       = (ushort_t*)alloc((size_t)N * 128 * 2);
    float*    C4         = (float*)alloc((size_t)N * 2 * 4);
    ushort_t* Wt1        = (ushort_t*)alloc((size_t)128 * 256 * 2);
    ushort_t* Wt2        = (ushort_t*)alloc((size_t)128 * 128 * 2);
    ushort_t* Wt3        = (ushort_t*)alloc((size_t)64 * 128 * 2);
    (void)ws_size;

    hipMemsetAsync(bkt_cursor, 0, (size_t)nbkt * 4, stream);

    // graph prep (bucketed)
    bin_kernel<<<(E + BIN_CHUNK - 1) / BIN_CHUNK, 256, 0, stream>>>(
        srcA, dstA, bkt_cursor, staging, E, nbkt);
    deg_from_staging_kernel<<<nbkt, 256, 0, stream>>>(staging, bkt_cursor, degi, dis, N);
    const int nb = (N + 1023) >> 10;
    scan_block_kernel<<<nb, 1024, 0, stream>>>(degi, row_start, bsums, N);
    scan_sums_kernel<<<1, 128, 0, stream>>>(bsums, nb);
    scan_add_kernel<<<(N + 256) / 256, 256, 0, stream>>>(row_start, bsums, N, nb);
    csr_build_kernel<<<nbkt, 256, 0, stream>>>(staging, bkt_cursor, row_start, csr_src, N);

    // weight transposes (bf16, padded) — one kernel
    wt_all_kernel<<<(57344 + 255) / 256, 256, 0, stream>>>(W1, W2, W3, Wt1, Wt2, Wt3);

    const int gx = (N + 127) / 128;
    const int aggBlocks128 = (N + 3) / 4;    // 4 waves/block, 1 node/wave
    const int aggBlocks32  = (N + 15) / 16;  // 16 nodes/block

    // layer 1: 256 -> 128 (A fp32, converted in staging; epilogue pre-scales)
    mfma_gemm<true><<<dim3(gx, 2), 256, 0, stream>>>(x, Wt1, bufA, dis, N, 256, 256, 256, 128, 128);
    aggregate128_kernel<128><<<aggBlocks128, 256, 0, stream>>>(
        bufA, row_start, csr_src, dis, b1, bufB, N);
    // layer 2: 128 -> 100 (padded)
    mfma_gemm<false><<<dim3(gx, 2), 256, 0, stream>>>(bufB, Wt2, bufA, dis, N, 128, 128, 128, 128, 128);
    aggregate128_kernel<100><<<aggBlocks128, 256, 0, stream>>>(
        bufA, row_start, csr_src, dis, b2, bufB, N);
    // layer 3: 128(pad) -> 32
    mfma_gemm<false><<<dim3(gx, 1), 256, 0, stream>>>(bufB, Wt3, bufA, dis, N, 128, 128, 128, 32, 32);
    aggregate32_kernel<<<aggBlocks32, 256, 0, stream>>>(
        bufA, row_start, csr_src, dis, b3, bufB, N);
    // layer 4: 32 -> 2, aggregate + softmax
    gemm32x2_kernel<<<(N + 255) / 256, 256, 0, stream>>>(bufB, W4, dis, C4, N);
    aggregate2_softmax_kernel<<<(N + 255) / 256, 256, 0, stream>>>(
        C4, row_start, csr_src, dis, b4, (float*)d_out, N);
}